// Round 2
// baseline (45240.570 us; speedup 1.0000x reference)
//
#include <hip/hip_runtime.h>

typedef __attribute__((ext_vector_type(8))) short short8;
typedef __attribute__((ext_vector_type(8))) __bf16 bf16x8;
typedef __attribute__((ext_vector_type(4))) float f32x4;

#define GENF 100
#define TCOND 50
#define BATCH 128
#define HID 1024
#define INP 171
#define INPAD 192
#define OUTN 171
#define OUTPAD 176
#define SPLITS 4
#define NTILES 64

static __device__ __forceinline__ unsigned short f2bf(float f) {
  unsigned u = __builtin_bit_cast(unsigned, f);
  u += 0x7fffu + ((u >> 16) & 1u);
  return (unsigned short)(u >> 16);
}
static __device__ __forceinline__ float bf2f(unsigned short s) {
  unsigned u = ((unsigned)s) << 16;
  return __builtin_bit_cast(float, u);
}
static __device__ __forceinline__ bf16x8 ld8(const unsigned short* p) {
  short8 v = *reinterpret_cast<const short8*>(p);
  return __builtin_bit_cast(bf16x8, v);
}
static __device__ __forceinline__ float sigm(float x) { return 1.f / (1.f + __expf(-x)); }

// Fused LSTM layer GEMM with split-K atomic accumulation + last-block cell epilogue.
// Grid: 256 blocks x 512 threads. Block = (n-tile nt: 16 cols x 4 gates, all 128 rows,
// K-split sp). Wave w handles m-tile w (16 rows). gates[] preloaded with bias;
// finisher applies cell math and resets gates to bias for the next step.
__global__ __launch_bounds__(512) void lstm_gemm_k(
    const unsigned short* __restrict__ xhi, const unsigned short* __restrict__ xlo,
    int ldx, int xiters,
    const unsigned short* __restrict__ wxhi, const unsigned short* __restrict__ wxlo,
    const unsigned short* __restrict__ hhi, const unsigned short* __restrict__ hlo,
    const unsigned short* __restrict__ whhi, const unsigned short* __restrict__ whlo,
    float* __restrict__ gates, const float* __restrict__ bias,
    float* __restrict__ c,
    unsigned short* __restrict__ ohhi, unsigned short* __restrict__ ohlo,
    unsigned* __restrict__ counters)
{
  const int nt = blockIdx.x & (NTILES - 1);
  const int sp = blockIdx.x >> 6;
  const int n0 = nt * 16;
  const int wave = threadIdx.x >> 6;
  const int lane = threadIdx.x & 63;
  const int m0 = wave * 16;
  const int row = lane & 15, kg = lane >> 4;

  const int NK = xiters + HID / 32;
  const int base = NK >> 2, rem = NK & 3;
  const int beg = sp * base + (sp < rem ? sp : rem);
  const int end = beg + base + (sp < rem ? 1 : 0);

  f32x4 z = {0.f, 0.f, 0.f, 0.f};
  f32x4 acc[4] = {z, z, z, z};

  // ---- x segment ----
  {
    int b = beg < xiters ? beg : xiters;
    int e = end < xiters ? end : xiters;
    if (b < e) {
      const unsigned short* pah = xhi + (size_t)(m0 + row) * ldx + kg * 8 + b * 32;
      const unsigned short* pal = xlo + (size_t)(m0 + row) * ldx + kg * 8 + b * 32;
      const unsigned short* pbh[4];
      const unsigned short* pbl[4];
#pragma unroll
      for (int g = 0; g < 4; ++g) {
        pbh[g] = wxhi + (size_t)(g * HID + n0 + row) * ldx + kg * 8 + b * 32;
        pbl[g] = wxlo + (size_t)(g * HID + n0 + row) * ldx + kg * 8 + b * 32;
      }
#pragma unroll 2
      for (int kk = b; kk < e; ++kk) {
        bf16x8 a1 = ld8(pah), a2 = ld8(pal);
        pah += 32; pal += 32;
#pragma unroll
        for (int g = 0; g < 4; ++g) {
          bf16x8 b1 = ld8(pbh[g]), b2 = ld8(pbl[g]);
          pbh[g] += 32; pbl[g] += 32;
          acc[g] = __builtin_amdgcn_mfma_f32_16x16x32_bf16(a1, b1, acc[g], 0, 0, 0);
          acc[g] = __builtin_amdgcn_mfma_f32_16x16x32_bf16(a2, b1, acc[g], 0, 0, 0);
          acc[g] = __builtin_amdgcn_mfma_f32_16x16x32_bf16(a1, b2, acc[g], 0, 0, 0);
        }
      }
    }
  }
  // ---- h segment ----
  {
    int b = beg - xiters; if (b < 0) b = 0;
    int e = end - xiters;
    if (b < e) {
      const unsigned short* pah = hhi + (size_t)(m0 + row) * HID + kg * 8 + b * 32;
      const unsigned short* pal = hlo + (size_t)(m0 + row) * HID + kg * 8 + b * 32;
      const unsigned short* pbh[4];
      const unsigned short* pbl[4];
#pragma unroll
      for (int g = 0; g < 4; ++g) {
        pbh[g] = whhi + (size_t)(g * HID + n0 + row) * HID + kg * 8 + b * 32;
        pbl[g] = whlo + (size_t)(g * HID + n0 + row) * HID + kg * 8 + b * 32;
      }
#pragma unroll 2
      for (int kk = b; kk < e; ++kk) {
        bf16x8 a1 = ld8(pah), a2 = ld8(pal);
        pah += 32; pal += 32;
#pragma unroll
        for (int g = 0; g < 4; ++g) {
          bf16x8 b1 = ld8(pbh[g]), b2 = ld8(pbl[g]);
          pbh[g] += 32; pbl[g] += 32;
          acc[g] = __builtin_amdgcn_mfma_f32_16x16x32_bf16(a1, b1, acc[g], 0, 0, 0);
          acc[g] = __builtin_amdgcn_mfma_f32_16x16x32_bf16(a2, b1, acc[g], 0, 0, 0);
          acc[g] = __builtin_amdgcn_mfma_f32_16x16x32_bf16(a1, b2, acc[g], 0, 0, 0);
        }
      }
    }
  }

  // ---- atomic accumulate partials into gates (bias-prefilled) ----
  // C/D layout: col = lane&15, row = (lane>>4)*4 + r
#pragma unroll
  for (int g = 0; g < 4; ++g)
#pragma unroll
    for (int r = 0; r < 4; ++r) {
      int m = m0 + kg * 4 + r;
      atomicAdd(&gates[(size_t)m * 4096 + g * HID + n0 + row], acc[g][r]);
    }

  __syncthreads();  // drains vmcnt: all this block's atomics complete
  __shared__ unsigned oldv;
  if (threadIdx.x == 0)
    oldv = __hip_atomic_fetch_add(&counters[nt], 1u, __ATOMIC_ACQ_REL, __HIP_MEMORY_SCOPE_AGENT);
  __syncthreads();
  if (oldv != SPLITS - 1) return;

  // ---- finisher: fused LSTM cell epilogue for this n-tile ----
  const int fc = threadIdx.x & 15;
  const int fr0 = threadIdx.x >> 4;  // 0..31
#pragma unroll
  for (int p = 0; p < 4; ++p) {
    int m = fr0 + p * 32;
    size_t gidx = (size_t)m * 4096 + n0 + fc;
    float vi = __hip_atomic_load(&gates[gidx], __ATOMIC_ACQUIRE, __HIP_MEMORY_SCOPE_AGENT);
    float vf = __hip_atomic_load(&gates[gidx + HID], __ATOMIC_ACQUIRE, __HIP_MEMORY_SCOPE_AGENT);
    float vg = __hip_atomic_load(&gates[gidx + 2 * HID], __ATOMIC_ACQUIRE, __HIP_MEMORY_SCOPE_AGENT);
    float vo = __hip_atomic_load(&gates[gidx + 3 * HID], __ATOMIC_ACQUIRE, __HIP_MEMORY_SCOPE_AGENT);
    float gi = sigm(vi), gf = sigm(vf), gg = tanhf(vg), go = sigm(vo);
    size_t sidx = (size_t)m * HID + n0 + fc;
    float cn = gf * c[sidx] + gi * gg;
    c[sidx] = cn;
    float h = go * tanhf(cn);
    unsigned short hh = f2bf(h);
    ohhi[sidx] = hh;
    ohlo[sidx] = f2bf(h - bf2f(hh));
    // reset gates region to bias for the next step (consumed after kernel boundary)
    gates[gidx] = bias[n0 + fc];
    gates[gidx + HID] = bias[HID + n0 + fc];
    gates[gidx + 2 * HID] = bias[2 * HID + n0 + fc];
    gates[gidx + 3 * HID] = bias[3 * HID + n0 + fc];
  }
  __syncthreads();
  if (threadIdx.x == 0)
    __hip_atomic_store(&counters[nt], 0u, __ATOMIC_RELAXED, __HIP_MEMORY_SCOPE_AGENT);
}

// Decoder: out = h2 @ w_dec^T + b_dec. 4 waves split K, LDS reduce.
__global__ __launch_bounds__(256) void dec_k(
    const unsigned short* __restrict__ hhi, const unsigned short* __restrict__ hlo,
    const unsigned short* __restrict__ wdhi, const unsigned short* __restrict__ wdlo,
    const float* __restrict__ bd,
    float* __restrict__ outp,
    unsigned short* __restrict__ fxhi, unsigned short* __restrict__ fxlo)
{
  const int wave = threadIdx.x >> 6, lane = threadIdx.x & 63;
  const int n0 = ((int)blockIdx.x % 11) * 16;
  const int m0 = ((int)blockIdx.x / 11) * 16;
  const int row = lane & 15, kg = lane >> 4;
  f32x4 acc = {0.f, 0.f, 0.f, 0.f};
  const unsigned short* pah = hhi + (size_t)(m0 + row) * HID + kg * 8 + wave * 256;
  const unsigned short* pal = hlo + (size_t)(m0 + row) * HID + kg * 8 + wave * 256;
  const unsigned short* pbh = wdhi + (size_t)(n0 + row) * HID + kg * 8 + wave * 256;
  const unsigned short* pbl = wdlo + (size_t)(n0 + row) * HID + kg * 8 + wave * 256;
#pragma unroll
  for (int kk = 0; kk < 8; ++kk) {
    int off = kk * 32;
    bf16x8 a1 = ld8(pah + off), a2 = ld8(pal + off);
    bf16x8 b1 = ld8(pbh + off), b2 = ld8(pbl + off);
    acc = __builtin_amdgcn_mfma_f32_16x16x32_bf16(a1, b1, acc, 0, 0, 0);
    acc = __builtin_amdgcn_mfma_f32_16x16x32_bf16(a2, b1, acc, 0, 0, 0);
    acc = __builtin_amdgcn_mfma_f32_16x16x32_bf16(a1, b2, acc, 0, 0, 0);
  }
  __shared__ f32x4 red[4][64];
  if (wave) red[wave][lane] = acc;
  __syncthreads();
  if (wave == 0) {
    acc += red[1][lane];
    acc += red[2][lane];
    acc += red[3][lane];
    const int col = lane & 15, rg = lane >> 4;
#pragma unroll
    for (int r = 0; r < 4; ++r) {
      int m = m0 + rg * 4 + r;
      int n = n0 + col;
      if (n < OUTN) {
        float v = acc[r] + bd[n];
        if (outp) outp[(size_t)m * (GENF * OUTN) + n] = v;
        unsigned short vh = f2bf(v);
        fxhi[(size_t)m * INPAD + n] = vh;
        fxlo[(size_t)m * INPAD + n] = f2bf(v - bf2f(vh));
      }
    }
  }
}

// ---- prep kernels ----
__global__ void cvt_hilo_k(const float* __restrict__ src, unsigned short* __restrict__ hi,
                           unsigned short* __restrict__ lo, int R, int C, int Rp, int Cp)
{
  int idx = blockIdx.x * 256 + threadIdx.x;
  if (idx >= Rp * Cp) return;
  int r = idx / Cp, c2 = idx - r * Cp;
  float v = (r < R && c2 < C) ? src[(size_t)r * C + c2] : 0.f;
  unsigned short h = f2bf(v);
  hi[idx] = h;
  lo[idx] = f2bf(v - bf2f(h));
}

__global__ void bias2_k(const float* __restrict__ a, const float* __restrict__ b,
                        float* __restrict__ dst, int n)
{
  int i = blockIdx.x * 256 + threadIdx.x;
  if (i < n) dst[i] = a[i] + b[i];
}

__global__ void biaspad_k(const float* __restrict__ a, float* __restrict__ dst, int n, int np)
{
  int i = blockIdx.x * 256 + threadIdx.x;
  if (i < np) dst[i] = (i < n) ? a[i] : 0.f;
}

__global__ void gates_init_k(float* __restrict__ g, const float* __restrict__ b)
{
  int idx = blockIdx.x * 256 + threadIdx.x;
  if (idx < BATCH * 4096) g[idx] = b[idx & 4095];
}

// initial_seq [B][T][IN] fp32 -> xcond hi/lo [T][B][INPAD] bf16 (zero-padded cols)
__global__ void xcond_k(const float* __restrict__ seq, unsigned short* __restrict__ xhi,
                        unsigned short* __restrict__ xlo)
{
  int idx = blockIdx.x * 256 + threadIdx.x;
  const int total = TCOND * BATCH * INPAD;
  if (idx >= total) return;
  int t = idx / (BATCH * INPAD);
  int rem = idx - t * (BATCH * INPAD);
  int b = rem / INPAD;
  int k = rem - b * INPAD;
  float v = (k < INP) ? seq[((size_t)b * TCOND + t) * INP + k] : 0.f;
  unsigned short h = f2bf(v);
  xhi[idx] = h;
  xlo[idx] = f2bf(v - bf2f(h));
}

extern "C" void kernel_launch(void* const* d_in, const int* in_sizes, int n_in,
                              void* d_out, int out_size, void* d_ws, size_t ws_size,
                              hipStream_t stream)
{
  (void)in_sizes; (void)n_in; (void)out_size;
  const float* seq   = (const float*)d_in[0];
  const float* w_ih1 = (const float*)d_in[2];
  const float* w_hh1 = (const float*)d_in[3];
  const float* b_ih1 = (const float*)d_in[4];
  const float* b_hh1 = (const float*)d_in[5];
  const float* w_ih2 = (const float*)d_in[6];
  const float* w_hh2 = (const float*)d_in[7];
  const float* b_ih2 = (const float*)d_in[8];
  const float* b_hh2 = (const float*)d_in[9];
  const float* w_ih3 = (const float*)d_in[10];
  const float* w_hh3 = (const float*)d_in[11];
  const float* b_ih3 = (const float*)d_in[12];
  const float* b_hh3 = (const float*)d_in[13];
  const float* w_dec = (const float*)d_in[14];
  const float* b_dec = (const float*)d_in[15];
  float* out = (float*)d_out;

  char* ws = (char*)d_ws;
  size_t off = 0;
  auto alloc = [&](size_t bytes) -> char* {
    off = (off + 255) & ~(size_t)255;
    char* p = ws + off;
    off += bytes;
    return p;
  };
  auto us = [&](size_t n) { return (unsigned short*)alloc(n * 2); };
  auto fl = [&](size_t n) { return (float*)alloc(n * 4); };

  unsigned short *wx1h = us((size_t)4096 * INPAD), *wx1l = us((size_t)4096 * INPAD);
  unsigned short *wh1h = us((size_t)4096 * HID), *wh1l = us((size_t)4096 * HID);
  unsigned short *wx2h = us((size_t)4096 * HID), *wx2l = us((size_t)4096 * HID);
  unsigned short *wh2h = us((size_t)4096 * HID), *wh2l = us((size_t)4096 * HID);
  unsigned short *wx3h = us((size_t)4096 * HID), *wx3l = us((size_t)4096 * HID);
  unsigned short *wh3h = us((size_t)4096 * HID), *wh3l = us((size_t)4096 * HID);
  unsigned short *wdh = us((size_t)OUTPAD * HID), *wdl = us((size_t)OUTPAD * HID);
  float *b1 = fl(4096), *b2 = fl(4096), *b3 = fl(4096), *bd = fl(OUTPAD);
  unsigned short *xch = us((size_t)TCOND * BATCH * INPAD), *xcl = us((size_t)TCOND * BATCH * INPAD);
  float *g1 = fl((size_t)BATCH * 4096), *g2 = fl((size_t)BATCH * 4096), *g3 = fl((size_t)BATCH * 4096);

  size_t state_beg = (off + 255) & ~(size_t)255;
  float *c0 = fl((size_t)BATCH * HID), *c1 = fl((size_t)BATCH * HID), *c2 = fl((size_t)BATCH * HID);
  unsigned short* Hh[3][2];
  unsigned short* Hl[3][2];
  for (int L = 0; L < 3; ++L)
    for (int p = 0; p < 2; ++p) {
      Hh[L][p] = us((size_t)BATCH * HID);
      Hl[L][p] = us((size_t)BATCH * HID);
    }
  unsigned short *fxh = us((size_t)BATCH * INPAD), *fxl = us((size_t)BATCH * INPAD);
  unsigned* counters = (unsigned*)alloc(3 * NTILES * 4);
  size_t state_end = off;

  if (off > ws_size) return;  // scratch too small; fail visibly

  // zero all recurrent state (c, h ping-pongs, frame, counters)
  hipMemsetAsync(ws + state_beg, 0, state_end - state_beg, stream);

  // ---- weight / input prep ----
  auto cvt = [&](const float* s, unsigned short* h, unsigned short* l, int R, int C, int Rp, int Cp) {
    int n = Rp * Cp;
    cvt_hilo_k<<<(n + 255) / 256, 256, 0, stream>>>(s, h, l, R, C, Rp, Cp);
  };
  cvt(w_ih1, wx1h, wx1l, 4096, INP, 4096, INPAD);
  cvt(w_hh1, wh1h, wh1l, 4096, HID, 4096, HID);
  cvt(w_ih2, wx2h, wx2l, 4096, HID, 4096, HID);
  cvt(w_hh2, wh2h, wh2l, 4096, HID, 4096, HID);
  cvt(w_ih3, wx3h, wx3l, 4096, HID, 4096, HID);
  cvt(w_hh3, wh3h, wh3l, 4096, HID, 4096, HID);
  cvt(w_dec, wdh, wdl, OUTN, HID, OUTPAD, HID);
  bias2_k<<<16, 256, 0, stream>>>(b_ih1, b_hh1, b1, 4096);
  bias2_k<<<16, 256, 0, stream>>>(b_ih2, b_hh2, b2, 4096);
  bias2_k<<<16, 256, 0, stream>>>(b_ih3, b_hh3, b3, 4096);
  biaspad_k<<<1, 256, 0, stream>>>(b_dec, bd, OUTN, OUTPAD);
  gates_init_k<<<2048, 256, 0, stream>>>(g1, b1);
  gates_init_k<<<2048, 256, 0, stream>>>(g2, b2);
  gates_init_k<<<2048, 256, 0, stream>>>(g3, b3);
  {
    int n = TCOND * BATCH * INPAD;
    xcond_k<<<(n + 255) / 256, 256, 0, stream>>>(seq, xch, xcl);
  }

  // ---- recurrent loop: 50 conditioning + 100 generation steps ----
  for (int s = 0; s < TCOND + GENF; ++s) {
    int pp = s & 1, np = pp ^ 1;
    const unsigned short *xh, *xl;
    if (s < TCOND) {
      xh = xch + (size_t)s * BATCH * INPAD;
      xl = xcl + (size_t)s * BATCH * INPAD;
    } else {
      xh = fxh;
      xl = fxl;
    }
    lstm_gemm_k<<<NTILES * SPLITS, 512, 0, stream>>>(xh, xl, INPAD, INPAD / 32, wx1h, wx1l,
        Hh[0][pp], Hl[0][pp], wh1h, wh1l, g1, b1, c0, Hh[0][np], Hl[0][np], counters);
    lstm_gemm_k<<<NTILES * SPLITS, 512, 0, stream>>>(Hh[0][np], Hl[0][np], HID, HID / 32, wx2h, wx2l,
        Hh[1][pp], Hl[1][pp], wh2h, wh2l, g2, b2, c1, Hh[1][np], Hl[1][np], counters + NTILES);
    lstm_gemm_k<<<NTILES * SPLITS, 512, 0, stream>>>(Hh[1][np], Hl[1][np], HID, HID / 32, wx3h, wx3l,
        Hh[2][pp], Hl[2][pp], wh3h, wh3l, g3, b3, c2, Hh[2][np], Hl[2][np], counters + 2 * NTILES);
    if (s == TCOND - 1) {
      dec_k<<<88, 256, 0, stream>>>(Hh[2][np], Hl[2][np], wdh, wdl, bd,
                                    (float*)nullptr, fxh, fxl);
    } else if (s >= TCOND) {
      dec_k<<<88, 256, 0, stream>>>(Hh[2][np], Hl[2][np], wdh, wdl, bd,
                                    out + (size_t)(s - TCOND) * OUTN, fxh, fxl);
    }
  }
}

// Round 3
// 16291.827 us; speedup vs baseline: 2.7769x; 2.7769x over previous
//
#include <hip/hip_runtime.h>

typedef __attribute__((ext_vector_type(8))) short short8;
typedef __attribute__((ext_vector_type(8))) __bf16 bf16x8;
typedef __attribute__((ext_vector_type(4))) float f32x4;

#define GENF 100
#define TCOND 50
#define BATCH 128
#define HID 1024
#define INP 171
#define INPAD 192
#define OUTN 171
#define OUTPAD 176
#define SPLITS 4
#define TILES 64

static __device__ __forceinline__ unsigned short f2bf(float f) {
  unsigned u = __builtin_bit_cast(unsigned, f);
  u += 0x7fffu + ((u >> 16) & 1u);
  return (unsigned short)(u >> 16);
}
static __device__ __forceinline__ float bf2f(unsigned short s) {
  unsigned u = ((unsigned)s) << 16;
  return __builtin_bit_cast(float, u);
}
static __device__ __forceinline__ bf16x8 ld8(const unsigned short* p) {
  short8 v = *reinterpret_cast<const short8*>(p);
  return __builtin_bit_cast(bf16x8, v);
}
static __device__ __forceinline__ float sigm(float x) { return 1.f / (1.f + __expf(-x)); }

// Fused LSTM layer: split-K GEMM (partials) + counter-elected finisher cell epilogue.
// W layout: [4096 perm rows (nh*4+g)][ldw] bf16 hi/lo, k-space = x-cols || h-cols.
// Grid: 256 blocks x 256 thr. block = (tile nt: 64 perm-cols, split sp). Wave = 16-col strip.
__global__ __launch_bounds__(256) void lstm_gemm_k(
    const unsigned short* __restrict__ xh_, const unsigned short* __restrict__ xl_,
    int ldx, int xc,
    const unsigned short* __restrict__ hh_, const unsigned short* __restrict__ hl_,
    const unsigned short* __restrict__ wH, const unsigned short* __restrict__ wL,
    int ldw, int NK,
    const float* __restrict__ bias,
    float* __restrict__ c,
    unsigned short* __restrict__ ohh, unsigned short* __restrict__ ohl,
    float* __restrict__ partials, unsigned* __restrict__ counters)
{
  __shared__ __align__(16) char smem[32768];  // 2 bufs x (hi 8K + lo 8K)
  const int t = threadIdx.x;
  const int lane = t & 63, wv = t >> 6;
  const int nt = blockIdx.x & (TILES - 1), sp = blockIdx.x >> 6;
  const int n0 = nt * 64 + wv * 16;  // wave's col strip (perm space)
  const int base = NK >> 2, rem = NK & 3;
  const int beg = sp * base + (sp < rem ? sp : rem);
  const int nit = base + (sp < rem ? 1 : 0);

  const int r_row = lane & 15, kg = lane >> 4;
  const int rslot = kg ^ (r_row & 3);  // swizzled 16B slot for ds_read
  const int srow = t >> 2;             // staging row (+ j*64)
  const size_t bcol = (size_t)(n0 + r_row) * ldw + kg * 8;

  auto stage = [&](int buf, int ck) {
    const unsigned short *sh, *sl;
    int ld, k0;
    if (ck < xc) { sh = xh_; sl = xl_; ld = ldx; k0 = ck * 32; }
    else { sh = hh_; sl = hl_; ld = HID; k0 = (ck - xc) * 32; }
#pragma unroll
    for (int j = 0; j < 2; ++j) {
      int rowp = j * 64 + srow;
      int slot = (t & 3) ^ (rowp & 3);  // inverse-swizzled global source
      const unsigned short* gh = sh + (size_t)rowp * ld + k0 + slot * 8;
      const unsigned short* gl = sl + (size_t)rowp * ld + k0 + slot * 8;
      char* dh = &smem[buf * 16384 + j * 4096 + wv * 1024];
      char* dl = &smem[buf * 16384 + 8192 + j * 4096 + wv * 1024];
      __builtin_amdgcn_global_load_lds((const __attribute__((address_space(1))) void*)gh,
                                       (__attribute__((address_space(3))) void*)dh, 16, 0, 0);
      __builtin_amdgcn_global_load_lds((const __attribute__((address_space(1))) void*)gl,
                                       (__attribute__((address_space(3))) void*)dl, 16, 0, 0);
    }
  };

  f32x4 zz = {0.f, 0.f, 0.f, 0.f};
  f32x4 acc[8] = {zz, zz, zz, zz, zz, zz, zz, zz};
  bf16x8 ah[8], al[8];

  stage(0, beg);
  bf16x8 bh_c = ld8(wH + bcol + (size_t)beg * 32);
  bf16x8 bl_c = ld8(wL + bcol + (size_t)beg * 32);
  __syncthreads();

  for (int i = 0; i < nit; ++i) {
    const int cbuf = (i & 1) * 16384;
    bf16x8 bh_n = bh_c, bl_n = bl_c;
    if (i + 1 < nit) {
      stage((i + 1) & 1, beg + i + 1);
      size_t ko = (size_t)(beg + i + 1) * 32;
      bh_n = ld8(wH + bcol + ko);
      bl_n = ld8(wL + bcol + ko);
    }
#pragma unroll
    for (int rg = 0; rg < 8; ++rg) {
      int ro = cbuf + (rg * 16 + r_row) * 64 + rslot * 16;
      ah[rg] = *reinterpret_cast<const bf16x8*>(&smem[ro]);
      al[rg] = *reinterpret_cast<const bf16x8*>(&smem[ro + 8192]);
    }
#pragma unroll
    for (int rg = 0; rg < 8; ++rg)
      acc[rg] = __builtin_amdgcn_mfma_f32_16x16x32_bf16(ah[rg], bh_c, acc[rg], 0, 0, 0);
#pragma unroll
    for (int rg = 0; rg < 8; ++rg)
      acc[rg] = __builtin_amdgcn_mfma_f32_16x16x32_bf16(al[rg], bh_c, acc[rg], 0, 0, 0);
#pragma unroll
    for (int rg = 0; rg < 8; ++rg)
      acc[rg] = __builtin_amdgcn_mfma_f32_16x16x32_bf16(ah[rg], bl_c, acc[rg], 0, 0, 0);
    __syncthreads();
    bh_c = bh_n; bl_c = bl_n;
  }

  // ---- store split partials (plain f32 stores) ----
  {
    float* pb = partials + (size_t)sp * (BATCH * 4096);
    const int cn = n0 + r_row;
    const int mb = kg * 4;
#pragma unroll
    for (int rg = 0; rg < 8; ++rg)
#pragma unroll
      for (int r = 0; r < 4; ++r)
        pb[(size_t)(rg * 16 + mb + r) * 4096 + cn] = acc[rg][r];
  }

  __syncthreads();  // drain stores
  __shared__ unsigned oldv;
  if (t == 0)
    oldv = __hip_atomic_fetch_add(&counters[nt], 1u, __ATOMIC_ACQ_REL, __HIP_MEMORY_SCOPE_AGENT);
  __syncthreads();
  if (oldv != SPLITS - 1) return;

  // ---- finisher: reduce splits + LSTM cell for this tile's 16 hid cols ----
  (void)__hip_atomic_load(&counters[nt], __ATOMIC_ACQUIRE, __HIP_MEMORY_SCOPE_AGENT);
  const int fc = t & 15, fm = t >> 4;
  const int nh = nt * 16 + fc;
  const f32x4 bv = *reinterpret_cast<const f32x4*>(&bias[nh * 4]);
#pragma unroll
  for (int p = 0; p < 8; ++p) {
    int m = fm + p * 16;
    size_t gi0 = (size_t)m * 4096 + nh * 4;
    f32x4 s = *reinterpret_cast<const f32x4*>(&partials[gi0]);
    s += *reinterpret_cast<const f32x4*>(&partials[gi0 + (size_t)1 * BATCH * 4096]);
    s += *reinterpret_cast<const f32x4*>(&partials[gi0 + (size_t)2 * BATCH * 4096]);
    s += *reinterpret_cast<const f32x4*>(&partials[gi0 + (size_t)3 * BATCH * 4096]);
    float gi = sigm(s[0] + bv[0]);
    float gf = sigm(s[1] + bv[1]);
    float gg = tanhf(s[2] + bv[2]);
    float go = sigm(s[3] + bv[3]);
    size_t sidx = (size_t)m * HID + nh;
    float cn2 = gf * c[sidx] + gi * gg;
    c[sidx] = cn2;
    float h = go * tanhf(cn2);
    unsigned short h16 = f2bf(h);
    ohh[sidx] = h16;
    ohl[sidx] = f2bf(h - bf2f(h16));
  }
  __syncthreads();
  if (t == 0)
    __hip_atomic_store(&counters[nt], 0u, __ATOMIC_RELAXED, __HIP_MEMORY_SCOPE_AGENT);
}

// Decoder: out = h2 @ w_dec^T + b_dec. 4 waves split K, LDS reduce.
__global__ __launch_bounds__(256) void dec_k(
    const unsigned short* __restrict__ hhi, const unsigned short* __restrict__ hlo,
    const unsigned short* __restrict__ wdhi, const unsigned short* __restrict__ wdlo,
    const float* __restrict__ bd,
    float* __restrict__ outp,
    unsigned short* __restrict__ fxhi, unsigned short* __restrict__ fxlo)
{
  const int wave = threadIdx.x >> 6, lane = threadIdx.x & 63;
  const int n0 = ((int)blockIdx.x % 11) * 16;
  const int m0 = ((int)blockIdx.x / 11) * 16;
  const int row = lane & 15, kg = lane >> 4;
  f32x4 acc = {0.f, 0.f, 0.f, 0.f};
  const unsigned short* pah = hhi + (size_t)(m0 + row) * HID + kg * 8 + wave * 256;
  const unsigned short* pal = hlo + (size_t)(m0 + row) * HID + kg * 8 + wave * 256;
  const unsigned short* pbh = wdhi + (size_t)(n0 + row) * HID + kg * 8 + wave * 256;
  const unsigned short* pbl = wdlo + (size_t)(n0 + row) * HID + kg * 8 + wave * 256;
#pragma unroll
  for (int kk = 0; kk < 8; ++kk) {
    int off = kk * 32;
    bf16x8 a1 = ld8(pah + off), a2 = ld8(pal + off);
    bf16x8 b1 = ld8(pbh + off), b2 = ld8(pbl + off);
    acc = __builtin_amdgcn_mfma_f32_16x16x32_bf16(a1, b1, acc, 0, 0, 0);
    acc = __builtin_amdgcn_mfma_f32_16x16x32_bf16(a2, b1, acc, 0, 0, 0);
    acc = __builtin_amdgcn_mfma_f32_16x16x32_bf16(a1, b2, acc, 0, 0, 0);
  }
  __shared__ f32x4 red[4][64];
  if (wave) red[wave][lane] = acc;
  __syncthreads();
  if (wave == 0) {
    acc += red[1][lane];
    acc += red[2][lane];
    acc += red[3][lane];
    const int col = lane & 15, rg = lane >> 4;
#pragma unroll
    for (int r = 0; r < 4; ++r) {
      int m = m0 + rg * 4 + r;
      int n = n0 + col;
      if (n < OUTN) {
        float v = acc[r] + bd[n];
        if (outp) outp[(size_t)m * (GENF * OUTN) + n] = v;
        unsigned short vh = f2bf(v);
        fxhi[(size_t)m * INPAD + n] = vh;
        fxlo[(size_t)m * INPAD + n] = f2bf(v - bf2f(vh));
      }
    }
  }
}

// ---- prep kernels ----
// LSTM weight: src [4096 gate-major][C] f32 -> dst rows permuted (nh*4+g), cols at
// [co, co+Cpad) of a [4096][dstride] hi/lo bf16 buffer; cols C..Cpad-1 zeroed.
__global__ void cvt_w_k(const float* __restrict__ src, unsigned short* __restrict__ hi,
                        unsigned short* __restrict__ lo, int C, int Cpad, int co, int dstride)
{
  int idx = blockIdx.x * 256 + threadIdx.x;
  if (idx >= 4096 * Cpad) return;
  int r = idx / Cpad, cc = idx - r * Cpad;
  float v = (cc < C) ? src[(size_t)r * C + cc] : 0.f;
  int rp = (r & 1023) * 4 + (r >> 10);
  size_t di = (size_t)rp * dstride + co + cc;
  unsigned short h = f2bf(v);
  hi[di] = h;
  lo[di] = f2bf(v - bf2f(h));
}

// dec weight: no perm, pad rows to Rp.
__global__ void cvt_hilo_k(const float* __restrict__ src, unsigned short* __restrict__ hi,
                           unsigned short* __restrict__ lo, int R, int C, int Rp, int Cp)
{
  int idx = blockIdx.x * 256 + threadIdx.x;
  if (idx >= Rp * Cp) return;
  int r = idx / Cp, c2 = idx - r * Cp;
  float v = (r < R && c2 < C) ? src[(size_t)r * C + c2] : 0.f;
  unsigned short h = f2bf(v);
  hi[idx] = h;
  lo[idx] = f2bf(v - bf2f(h));
}

__global__ void bias_perm_k(const float* __restrict__ a, const float* __restrict__ b,
                            float* __restrict__ dst)
{
  int i = blockIdx.x * 256 + threadIdx.x;
  if (i < 4096) dst[(i & 1023) * 4 + (i >> 10)] = a[i] + b[i];
}

__global__ void biaspad_k(const float* __restrict__ a, float* __restrict__ dst, int n, int np)
{
  int i = blockIdx.x * 256 + threadIdx.x;
  if (i < np) dst[i] = (i < n) ? a[i] : 0.f;
}

// initial_seq [B][T][IN] fp32 -> xcond hi/lo [T][B][INPAD] bf16 (zero-padded cols)
__global__ void xcond_k(const float* __restrict__ seq, unsigned short* __restrict__ xhi,
                        unsigned short* __restrict__ xlo)
{
  int idx = blockIdx.x * 256 + threadIdx.x;
  const int total = TCOND * BATCH * INPAD;
  if (idx >= total) return;
  int t = idx / (BATCH * INPAD);
  int rem = idx - t * (BATCH * INPAD);
  int b = rem / INPAD;
  int k = rem - b * INPAD;
  float v = (k < INP) ? seq[((size_t)b * TCOND + t) * INP + k] : 0.f;
  unsigned short h = f2bf(v);
  xhi[idx] = h;
  xlo[idx] = f2bf(v - bf2f(h));
}

extern "C" void kernel_launch(void* const* d_in, const int* in_sizes, int n_in,
                              void* d_out, int out_size, void* d_ws, size_t ws_size,
                              hipStream_t stream)
{
  (void)in_sizes; (void)n_in; (void)out_size;
  const float* seq   = (const float*)d_in[0];
  const float* w_ih1 = (const float*)d_in[2];
  const float* w_hh1 = (const float*)d_in[3];
  const float* b_ih1 = (const float*)d_in[4];
  const float* b_hh1 = (const float*)d_in[5];
  const float* w_ih2 = (const float*)d_in[6];
  const float* w_hh2 = (const float*)d_in[7];
  const float* b_ih2 = (const float*)d_in[8];
  const float* b_hh2 = (const float*)d_in[9];
  const float* w_ih3 = (const float*)d_in[10];
  const float* w_hh3 = (const float*)d_in[11];
  const float* b_ih3 = (const float*)d_in[12];
  const float* b_hh3 = (const float*)d_in[13];
  const float* w_dec = (const float*)d_in[14];
  const float* b_dec = (const float*)d_in[15];
  float* out = (float*)d_out;

  char* ws = (char*)d_ws;
  size_t off = 0;
  auto alloc = [&](size_t bytes) -> char* {
    off = (off + 255) & ~(size_t)255;
    char* p = ws + off;
    off += bytes;
    return p;
  };
  auto us = [&](size_t n) { return (unsigned short*)alloc(n * 2); };
  auto fl = [&](size_t n) { return (float*)alloc(n * 4); };

  const int K1 = INPAD + HID;  // 1216
  const int K2 = 2 * HID;      // 2048
  unsigned short *W1h = us((size_t)4096 * K1), *W1l = us((size_t)4096 * K1);
  unsigned short *W2h = us((size_t)4096 * K2), *W2l = us((size_t)4096 * K2);
  unsigned short *W3h = us((size_t)4096 * K2), *W3l = us((size_t)4096 * K2);
  unsigned short *wdh = us((size_t)OUTPAD * HID), *wdl = us((size_t)OUTPAD * HID);
  float *b1 = fl(4096), *b2 = fl(4096), *b3 = fl(4096), *bd = fl(OUTPAD);
  unsigned short *xch = us((size_t)TCOND * BATCH * INPAD), *xcl = us((size_t)TCOND * BATCH * INPAD);
  float* partials = fl((size_t)SPLITS * BATCH * 4096);

  size_t state_beg = (off + 255) & ~(size_t)255;
  float *c0 = fl((size_t)BATCH * HID), *c1 = fl((size_t)BATCH * HID), *c2 = fl((size_t)BATCH * HID);
  unsigned short* Hh[3][2];
  unsigned short* Hl[3][2];
  for (int L = 0; L < 3; ++L)
    for (int p = 0; p < 2; ++p) {
      Hh[L][p] = us((size_t)BATCH * HID);
      Hl[L][p] = us((size_t)BATCH * HID);
    }
  unsigned short *fxh = us((size_t)BATCH * INPAD), *fxl = us((size_t)BATCH * INPAD);
  unsigned* counters = (unsigned*)alloc(TILES * 4);
  size_t state_end = off;

  if (off > ws_size) return;  // scratch too small; fail visibly

  hipMemsetAsync(ws + state_beg, 0, state_end - state_beg, stream);

  // ---- weight / input prep ----
  auto cw = [&](const float* s, unsigned short* h, unsigned short* l, int C, int Cpad, int co, int ds2) {
    int n = 4096 * Cpad;
    cvt_w_k<<<(n + 255) / 256, 256, 0, stream>>>(s, h, l, C, Cpad, co, ds2);
  };
  cw(w_ih1, W1h, W1l, INP, INPAD, 0, K1);
  cw(w_hh1, W1h, W1l, HID, HID, INPAD, K1);
  cw(w_ih2, W2h, W2l, HID, HID, 0, K2);
  cw(w_hh2, W2h, W2l, HID, HID, HID, K2);
  cw(w_ih3, W3h, W3l, HID, HID, 0, K2);
  cw(w_hh3, W3h, W3l, HID, HID, HID, K2);
  {
    int n = OUTPAD * HID;
    cvt_hilo_k<<<(n + 255) / 256, 256, 0, stream>>>(w_dec, wdh, wdl, OUTN, HID, OUTPAD, HID);
  }
  bias_perm_k<<<16, 256, 0, stream>>>(b_ih1, b_hh1, b1);
  bias_perm_k<<<16, 256, 0, stream>>>(b_ih2, b_hh2, b2);
  bias_perm_k<<<16, 256, 0, stream>>>(b_ih3, b_hh3, b3);
  biaspad_k<<<1, 256, 0, stream>>>(b_dec, bd, OUTN, OUTPAD);
  {
    int n = TCOND * BATCH * INPAD;
    xcond_k<<<(n + 255) / 256, 256, 0, stream>>>(seq, xch, xcl);
  }

  // ---- recurrent loop ----
  for (int s = 0; s < TCOND + GENF; ++s) {
    int pp = s & 1, np = pp ^ 1;
    const unsigned short *xh, *xl;
    if (s < TCOND) {
      xh = xch + (size_t)s * BATCH * INPAD;
      xl = xcl + (size_t)s * BATCH * INPAD;
    } else {
      xh = fxh;
      xl = fxl;
    }
    lstm_gemm_k<<<TILES * SPLITS, 256, 0, stream>>>(xh, xl, INPAD, INPAD / 32,
        Hh[0][pp], Hl[0][pp], W1h, W1l, K1, K1 / 32, b1, c0,
        Hh[0][np], Hl[0][np], partials, counters);
    lstm_gemm_k<<<TILES * SPLITS, 256, 0, stream>>>(Hh[0][np], Hl[0][np], HID, HID / 32,
        Hh[1][pp], Hl[1][pp], W2h, W2l, K2, K2 / 32, b2, c1,
        Hh[1][np], Hl[1][np], partials, counters);
    lstm_gemm_k<<<TILES * SPLITS, 256, 0, stream>>>(Hh[1][np], Hl[1][np], HID, HID / 32,
        Hh[2][pp], Hl[2][pp], W3h, W3l, K2, K2 / 32, b3, c2,
        Hh[2][np], Hl[2][np], partials, counters);
    if (s == TCOND - 1) {
      dec_k<<<88, 256, 0, stream>>>(Hh[2][np], Hl[2][np], wdh, wdl, bd,
                                    (float*)nullptr, fxh, fxl);
    } else if (s >= TCOND) {
      dec_k<<<88, 256, 0, stream>>>(Hh[2][np], Hl[2][np], wdh, wdl, bd,
                                    out + (size_t)(s - TCOND) * OUTN, fxh, fxl);
    }
  }
}